// Round 4
// baseline (743.055 us; speedup 1.0000x reference)
//
#include <hip/hip_runtime.h>
#include <math.h>

#define NN 4096
#define NITER 20

// u_0 = 1.0 (all-ones row scaling). Everything else in ws is written before read.
__global__ void k_init(double* u) {
    int i = blockIdx.x * blockDim.x + threadIdx.x;
    if (i < NN) u[i] = 1.0;
}

// E = exp(W), fp32, float4-vectorized. (fp32 storage: expf's ~1ulp is below the
// 3e-8 quantization the fp32 store imposes anyway.)
__global__ __launch_bounds__(256) void k_exp(const float* __restrict__ W,
                                             float* __restrict__ E) {
    size_t i = (size_t)(blockIdx.x * blockDim.x + threadIdx.x) * 4;
    float4 w = *(const float4*)(W + i);
    float4 e;
    e.x = expf(w.x);
    e.y = expf(w.y);
    e.z = expf(w.z);
    e.w = expf(w.w);
    *(float4*)(E + i) = e;
}

// Column pass, deterministic: per-slab partials instead of atomics.
// grid = 1024: 16 col-groups (256 cols) x 64 row-slabs (64 rows). block = 256.
// partials[s][j] = sum over slab-s rows of E[i][j] * u[i].
__global__ __launch_bounds__(256) void k_colp(const float* __restrict__ E,
                                              const double* __restrict__ u,
                                              double* __restrict__ partials) {
    const int l  = threadIdx.x & 63;
    const int wv = threadIdx.x >> 6;
    const int g  = blockIdx.x & 15;    // column group
    const int s  = blockIdx.x >> 4;    // row slab

    const float4* ep = (const float4*)(E + (size_t)(s * 64 + wv) * NN + g * 256) + l;
    const double* up = u + s * 64 + wv;

    double a0 = 0.0, a1 = 0.0, a2 = 0.0, a3 = 0.0;
    #pragma unroll
    for (int k = 0; k < 16; ++k) {
        float4 e = ep[(size_t)k * 4 * (NN / 4)];   // rows s*64 + wv + 4k, coalesced 1KB/wave
        double uu = up[k * 4];                      // wave-uniform broadcast
        a0 = fma((double)e.x, uu, a0);
        a1 = fma((double)e.y, uu, a1);
        a2 = fma((double)e.z, uu, a2);
        a3 = fma((double)e.w, uu, a3);
    }

    __shared__ double sdata[1024];
    const int t = threadIdx.x;
    sdata[t * 4 + 0] = a0;
    sdata[t * 4 + 1] = a1;
    sdata[t * 4 + 2] = a2;
    sdata[t * 4 + 3] = a3;
    __syncthreads();
    if (t < 256) {
        // column offset t within group: one entry per wave, fixed order
        double ssum = (sdata[t] + sdata[256 + t]) + (sdata[512 + t] + sdata[768 + t]);
        partials[(size_t)s * NN + g * 256 + t] = ssum;   // plain store, no atomics
    }
}

// Fixed-order slab reduction: scol[j] = sum_s partials[s][j]; vf[j] = 1/scol[j] (fp32).
// Bit-deterministic: loop order s = 0..63 regardless of scheduling.
__global__ __launch_bounds__(64) void k_vred(const double* __restrict__ partials,
                                             double* __restrict__ scol,
                                             float* __restrict__ vf) {
    const int j = blockIdx.x * 64 + threadIdx.x;
    double acc = 0.0;
    #pragma unroll
    for (int s = 0; s < 64; ++s)
        acc += partials[(size_t)s * NN + j];   // coalesced 512B/wave per s
    scol[j] = acc;
    vf[j] = (float)(1.0 / acc);
}

// Row pass: u[i] = 1 / sum_j E[i][j] * vf[j]. One wave per row, deterministic.
__global__ __launch_bounds__(1024) void k_rowu(const float* __restrict__ E,
                                               const float* __restrict__ vf,
                                               double* __restrict__ u) {
    __shared__ float v[NN];  // 16 KiB
    ((float4*)v)[threadIdx.x] = ((const float4*)vf)[threadIdx.x];
    __syncthreads();

    const int l  = threadIdx.x & 63;
    const int wv = threadIdx.x >> 6;
    const int i  = blockIdx.x * 16 + wv;
    const float4* ep = (const float4*)(E + (size_t)i * NN) + l;
    const float4* vp = (const float4*)v + l;

    double a0 = 0.0, a1 = 0.0, a2 = 0.0, a3 = 0.0;
    #pragma unroll
    for (int k = 0; k < 16; ++k) {
        float4 e  = ep[k * 64];    // coalesced 1KB/wave
        float4 vv = vp[k * 64];    // ds_read_b128, conflict-free
        a0 = fma((double)e.x, (double)vv.x, a0);
        a1 = fma((double)e.y, (double)vv.y, a1);
        a2 = fma((double)e.z, (double)vv.z, a2);
        a3 = fma((double)e.w, (double)vv.w, a3);
    }
    double acc = (a0 + a1) + (a2 + a3);
    for (int off = 32; off > 0; off >>= 1)
        acc += __shfl_xor(acc, off, 64);       // fixed butterfly order
    if (l == 0) u[i] = 1.0 / acc;
}

// Final: P = exp(W + lv[j] + lu[i]); hard = one-hot(argmax_j (W + lv[j])).
// lv[j] = -log(scol[j]);  lu[i] = log(u[i]).
__global__ __launch_bounds__(1024) void k_final(const float* __restrict__ W,
                                                const double* __restrict__ scol,
                                                const double* __restrict__ u,
                                                float* __restrict__ P,
                                                float* __restrict__ H) {
    __shared__ double lv[NN];  // 32 KiB
    for (int j = threadIdx.x; j < NN; j += 1024)
        lv[j] = -log(scol[j]);
    __syncthreads();

    const int l  = threadIdx.x & 63;
    const int wv = threadIdx.x >> 6;
    const int i  = blockIdx.x * 16 + wv;
    const float4* wp = (const float4*)(W + (size_t)i * NN) + l;
    float4* pp = (float4*)(P + (size_t)i * NN) + l;
    float4* hp = (float4*)(H + (size_t)i * NN) + l;
    const double lu = log(u[i]);   // = -R[i]

    double besty = -1e300;
    int bestj = 0;
    #pragma unroll 4
    for (int k = 0; k < 16; ++k) {
        float4 w = wp[k * 64];
        int jb = k * 256 + l * 4;
        double y0 = (double)w.x + lv[jb + 0];
        double y1 = (double)w.y + lv[jb + 1];
        double y2 = (double)w.z + lv[jb + 2];
        double y3 = (double)w.w + lv[jb + 3];
        float4 pv;
        pv.x = expf((float)(y0 + lu));
        pv.y = expf((float)(y1 + lu));
        pv.z = expf((float)(y2 + lu));
        pv.w = expf((float)(y3 + lu));
        pp[k * 64] = pv;
        if (y0 > besty) { besty = y0; bestj = jb + 0; }   // strict > keeps first index
        if (y1 > besty) { besty = y1; bestj = jb + 1; }
        if (y2 > besty) { besty = y2; bestj = jb + 2; }
        if (y3 > besty) { besty = y3; bestj = jb + 3; }
    }
    for (int off = 32; off > 0; off >>= 1) {
        double oy = __shfl_xor(besty, off, 64);
        int    oj = __shfl_xor(bestj, off, 64);
        if (oy > besty || (oy == besty && oj < bestj)) { besty = oy; bestj = oj; }
    }
    #pragma unroll 4
    for (int k = 0; k < 16; ++k) {
        int jb = k * 256 + l * 4;
        float4 hv;
        hv.x = (jb + 0 == bestj) ? 1.0f : 0.0f;
        hv.y = (jb + 1 == bestj) ? 1.0f : 0.0f;
        hv.z = (jb + 2 == bestj) ? 1.0f : 0.0f;
        hv.w = (jb + 3 == bestj) ? 1.0f : 0.0f;
        hp[k * 64] = hv;
    }
}

extern "C" void kernel_launch(void* const* d_in, const int* in_sizes, int n_in,
                              void* d_out, int out_size, void* d_ws, size_t ws_size,
                              hipStream_t stream) {
    const float* W = (const float*)d_in[0];
    float* out0 = (float*)d_out;                  // P_hat
    float* out1 = out0 + (size_t)NN * NN;         // P_hat_hard

    float*  E        = (float*)d_ws;                         // NN*NN fp32 (64 MiB)
    double* partials = (double*)(E + (size_t)NN * NN);       // 64*NN fp64 (2 MiB)
    double* u        = partials + (size_t)64 * NN;           // NN fp64
    double* scol     = u + NN;                               // NN fp64
    float*  vf       = (float*)(scol + NN);                  // NN fp32

    k_init<<<(NN + 255) / 256, 256, 0, stream>>>(u);
    k_exp<<<NN * NN / 4 / 256, 256, 0, stream>>>(W, E);

    for (int t = 0; t < NITER; ++t) {
        k_colp<<<1024, 256, 0, stream>>>(E, u, partials);
        k_vred<<<64, 64, 0, stream>>>(partials, scol, vf);
        k_rowu<<<256, 1024, 0, stream>>>(E, vf, u);
    }
    k_final<<<256, 1024, 0, stream>>>(W, scol, u, out0, out1);
}